// Round 1
// baseline (3462.966 us; speedup 1.0000x reference)
//
#include <hip/hip_runtime.h>

typedef unsigned short u16;
typedef unsigned int   u32;
typedef unsigned long long u64;

#define B_    8
#define N_    8192
#define CIN   64
#define COUT  128
#define NS    2048
#define K_    32
#define LDSPAD 136   // 128 + 8 bf16: breaks bank conflicts on column stride

#define FPS_NBLK 4            // blocks per batch (same-XCD: grid ids b, b+8, b+16, b+24)
#define FPS_PPB  (N_/FPS_NBLK) // 2048 points per block
#define FPS_PPT  (FPS_PPB/512) // 4 points per thread

typedef __attribute__((ext_vector_type(8))) short short8;
typedef __attribute__((ext_vector_type(4))) float f32x4;

#define MFMA16(a,b,c) __builtin_amdgcn_mfma_f32_16x16x32_bf16(a,b,c,0,0,0)

__device__ __forceinline__ u16 f2bf(float f){
  u32 u = __float_as_uint(f);
  return (u16)((u + 0x7FFFu + ((u >> 16) & 1u)) >> 16);   // RNE, finite values only
}
__device__ __forceinline__ float bf2f(u16 h){ u32 u = ((u32)h) << 16; return __uint_as_float(u); }
__device__ __forceinline__ u32 pack2bf(float lo, float hi){ return (u32)f2bf(lo) | ((u32)f2bf(hi) << 16); }

// ---------------------------------------------------------------------------
// Weight f32 -> bf16 conversion (one-time prep into ws)
// ---------------------------------------------------------------------------
__global__ void wcvt_kernel(const float* __restrict__ s, u16* __restrict__ d, int n){
  int i = blockIdx.x * 256 + threadIdx.x;
  if (i < n) d[i] = f2bf(s[i]);
}

// zero the cross-block FPS flag array (must run before fps_kernel每 launch:
// graph replay reuses ws, stale ready-bits would break the spin protocol)
__global__ void fps_flags_clear_kernel(uint4* __restrict__ p, int n){
  int i = blockIdx.x * 256 + threadIdx.x;
  if (i < n) p[i] = make_uint4(0u, 0u, 0u, 0u);
}

// ---------------------------------------------------------------------------
// BN constants: scale = g/sqrt(v+eps), bias = b - m*scale  (all f32 inputs)
// set order: 0=te, 1/2=pre0.bn1/bn2, 3/4=pre1.bn1/bn2, 5/6=pos0, 7/8=pos1
// ---------------------------------------------------------------------------
struct BnPtrs { const float* g[9]; const float* b[9]; const float* m[9]; const float* v[9]; };

__global__ void bn_pre_kernel(BnPtrs p, float* __restrict__ bns){
  int set = blockIdx.x, c = threadIdx.x;
  float sc = p.g[set][c] / sqrtf(p.v[set][c] + 1e-5f);
  bns[set*256 + c]       = sc;
  bns[set*256 + 128 + c] = p.b[set][c] - p.m[set][c] * sc;
}

// ---------------------------------------------------------------------------
// FPS v6: multi-CU. v5 was VALU-issue-bound at ~94% on its 8 CUs (VALUBusy
// 2.95% vs 3.125% ceiling), ~2600 cyc/step. Split each batch over 4 blocks
// (4 pts/thread in REGISTERS — also kills the 12 ds_read_b128/step), exchange
// per-block winners via write-once global u64 flags:
//   key = (1<<63 ready) | (distbits<<13) | (8191 - idx)
// u64 max over keys == exact np.argmax (max dist, tie -> lowest global index).
// blockIdx: batch = id&7, quarter = id>>3  =>  the 4 blocks of a batch map to
// the SAME XCD under round-robin dispatch (id mod 8) -> flag spin stays in one
// L2. Flags are per-(block,step), written once: no ABA; cleared each launch.
// Full coord copy stays in LDS for the winner-coordinate broadcast.
// Exact f32 (contract off); distance arithmetic bit-identical to v5.
// ---------------------------------------------------------------------------
#define DPP_UMAX(x, ctrl) { \
  u32 o = (u32)__builtin_amdgcn_update_dpp((int)(x), (int)(x), ctrl, 0xf, 0xf, false); \
  x = (o > x) ? o : x; }

__device__ __forceinline__ u32 wave_umax63(u32 x){
  DPP_UMAX(x, 0x111)  // row_shr:1
  DPP_UMAX(x, 0x112)  // row_shr:2
  DPP_UMAX(x, 0x114)  // row_shr:4
  DPP_UMAX(x, 0x118)  // row_shr:8
  DPP_UMAX(x, 0x142)  // row_bcast:15
  DPP_UMAX(x, 0x143)  // row_bcast:31
  return (u32)__builtin_amdgcn_readlane((int)x, 63);
}

__global__ __launch_bounds__(512) void fps_kernel(const float* __restrict__ xyz,
                                                  int* __restrict__ fps_idx,
                                                  u64* __restrict__ flags){
  #pragma clang fp contract(off)
  const int bq = blockIdx.x;          // 0..31
  const int b  = bq & 7;              // batch
  const int q  = bq >> 3;             // quarter 0..3 (stride-8 ids: same XCD)
  const int t  = threadIdx.x;
  const int lane = t & 63, wv = t >> 6;
  const float* xb = xyz + (size_t)b * N_ * 3;
  __shared__ __align__(16) float PX[N_], PY[N_], PZ[N_];   // 96 KB full copy
  __shared__ u64 kArr[2][8];
  #pragma unroll
  for (int i = 0; i < 16; ++i){        // one-time transposed stage-in
    int p = t*16 + i;
    PX[p] = xb[p*3 + 0];
    PY[p] = xb[p*3 + 1];
    PZ[p] = xb[p*3 + 2];
  }
  if (q == 0 && t == 0) fps_idx[b*NS] = 0;
  __syncthreads();

  // this block's 4 scan points live in registers
  const int base = q*FPS_PPB + t*4;
  const f32x4 px = *(const f32x4*)(PX + base);
  const f32x4 py = *(const f32x4*)(PY + base);
  const f32x4 pz = *(const f32x4*)(PZ + base);
  f32x4 D = {1e10f, 1e10f, 1e10f, 1e10f};
  float lx = PX[0], ly = PY[0], lz = PZ[0];   // point 0 is the seed

  u64* myflag = flags + ((size_t)(b*FPS_NBLK + q)) * NS;
  u64* nf0 = flags + ((size_t)(b*FPS_NBLK + ((q+1)&3))) * NS;
  u64* nf1 = flags + ((size_t)(b*FPS_NBLK + ((q+2)&3))) * NS;
  u64* nf2 = flags + ((size_t)(b*FPS_NBLK + ((q+3)&3))) * NS;

  for (int s = 0; s < NS - 1; ++s){
    u32 tb = 0;                        // dist >= 0 -> bits valid for umax
    #pragma unroll
    for (int i = 0; i < 4; ++i){
      float dx = px[i] - lx;
      float dy = py[i] - ly;
      float dz = pz[i] - lz;
      float t0 = dx*dx;
      float t1 = dy*dy;
      float t2 = dz*dz;
      float dd = (t0 + t1) + t2;       // same assoc as np.sum axis=-1
      float nd = fminf(D[i], dd);
      D[i] = nd;
      u32 nb = __float_as_uint(nd);
      tb = (nb > tb) ? nb : tb;
    }
    const u32 wmax = wave_umax63(tb);            // 6 VALU DPP ops + readlane
    const u64 mask = __ballot(tb == wmax);
    const int fl = __ffsll((long long)mask) - 1; // lowest lane = lowest index
    const int sl = s & 1;
    if (lane == fl){
      int kk = 3;                                 // smallest matching i wins
      kk = (__float_as_uint(D[2]) == wmax) ? 2 : kk;
      kk = (__float_as_uint(D[1]) == wmax) ? 1 : kk;
      kk = (__float_as_uint(D[0]) == wmax) ? 0 : kk;
      const int pi = base + kk;
      kArr[sl][wv] = (1ull << 63) | ((u64)wmax << 13) | (u64)(8191 - pi);
    }
    // speculative first poll: issues pre-barrier, completes under barrier+combine
    u64 k0 = __hip_atomic_load(nf0 + s, __ATOMIC_RELAXED, __HIP_MEMORY_SCOPE_AGENT);
    u64 k1 = __hip_atomic_load(nf1 + s, __ATOMIC_RELAXED, __HIP_MEMORY_SCOPE_AGENT);
    u64 k2 = __hip_atomic_load(nf2 + s, __ATOMIC_RELAXED, __HIP_MEMORY_SCOPE_AGENT);
    __syncthreads();
    u64 win = kArr[sl][0];
    #pragma unroll
    for (int w = 1; w < 8; ++w){
      u64 o = kArr[sl][w];
      win = (o > win) ? o : win;
    }
    if (lane == 0)                               // every wave publishes (same value):
      __hip_atomic_store(myflag + s, win, __ATOMIC_RELAXED, __HIP_MEMORY_SCOPE_AGENT);
    while (!((k0 & k1 & k2) >> 63)){
      if (!(k0 >> 63)) k0 = __hip_atomic_load(nf0 + s, __ATOMIC_RELAXED, __HIP_MEMORY_SCOPE_AGENT);
      if (!(k1 >> 63)) k1 = __hip_atomic_load(nf1 + s, __ATOMIC_RELAXED, __HIP_MEMORY_SCOPE_AGENT);
      if (!(k2 >> 63)) k2 = __hip_atomic_load(nf2 + s, __ATOMIC_RELAXED, __HIP_MEMORY_SCOPE_AGENT);
    }
    win = (k0 > win) ? k0 : win;
    win = (k1 > win) ? k1 : win;
    win = (k2 > win) ? k2 : win;
    const int pi = 8191 - (int)(win & 0x1FFFull);
    lx = PX[pi]; ly = PY[pi]; lz = PZ[pi];       // broadcast LDS read (same addr)
    if (q == 0 && t == 0) fps_idx[b*NS + s + 1] = pi;
  }
}

// ---------------------------------------------------------------------------
// kNN: one wave per center, sorted 64-slot (d2,idx) lane-list, threshold =
// slot 31. Ballot pre-filter per 64-pt chunk, shfl_up sorted insertion.
// Exact f32 distances + lex (d2,idx) ties == stable top_k neighbor set.
// Also emits new_xyz (exact f32 gather).
// ---------------------------------------------------------------------------
__global__ __launch_bounds__(256) void knn_kernel(const float* __restrict__ xyz, const int* __restrict__ fps_idx,
                                                  int* __restrict__ knn, float* __restrict__ out_xyz){
  #pragma clang fp contract(off)
  const int wid = threadIdx.x >> 6, lane = threadIdx.x & 63;
  const int cg = blockIdx.x * 4 + wid;
  const int b = cg >> 11;
  const float* xb = xyz + (size_t)b * N_ * 3;
  const int ci = fps_idx[cg] & (N_ - 1);      // clamp: fault-proof
  const float cx = xb[ci*3], cy = xb[ci*3+1], cz = xb[ci*3+2];
  if (lane < 3) out_xyz[cg*3 + lane] = xb[ci*3 + lane];

  float rd = __uint_as_float(0x7F800000u); int ri = 0x7FFFFFFF;
  float r31d = rd; int r31i = ri;
  for (int c = 0; c < N_/64; ++c){
    const int pid = c*64 + lane;
    float dx = xb[pid*3]   - cx;
    float dy = xb[pid*3+1] - cy;
    float dz = xb[pid*3+2] - cz;
    float t0 = dx*dx, t1 = dy*dy, t2 = dz*dz;
    float d2 = (t0 + t1) + t2;
    u64 m = __ballot((d2 < r31d) || (d2 == r31d && pid < r31i));
    while (m){
      int l = __ffsll((long long)m) - 1; m &= m - 1;
      float v = __shfl(d2, l); int vi = c*64 + l;
      if (!((v < r31d) || (v == r31d && vi < r31i))) continue;  // re-check vs updated threshold
      bool lt = (rd < v) || (rd == v && ri < vi);
      int pos = __popcll(__ballot(lt));
      float prd = __shfl_up(rd, 1); int pri = __shfl_up(ri, 1);
      if (lane == pos){ rd = v; ri = vi; }
      else if (lane > pos){ rd = prd; ri = pri; }
      r31d = __shfl(rd, 31); r31i = __shfl(ri, 31);
    }
  }
  if (lane < K_) knn[(size_t)cg * K_ + lane] = ri;
}

// ---------------------------------------------------------------------------
// Conv stack helpers. Wave-private X tile [32 cols][136 ch] bf16 in LDS.
// MFMA 16x16x32 bf16: A[m=lane&15][k=q*8+j], B[k=q*8+j][n=lane&15],
// D col=lane&15, row=q*4+reg (m89-verified layouts). W is bf16 (pre-converted).
// ---------------------------------------------------------------------------
__device__ __forceinline__ void zero_acc(f32x4 acc[8][2]){
  #pragma unroll
  for (int mt = 0; mt < 8; ++mt)
    #pragma unroll
    for (int nt = 0; nt < 2; ++nt){
      acc[mt][nt][0] = 0.f; acc[mt][nt][1] = 0.f; acc[mt][nt][2] = 0.f; acc[mt][nt][3] = 0.f;
    }
}

__device__ __forceinline__ void conv_step(const u16* __restrict__ W, const u16* __restrict__ Xw,
                                          int q, int l15, f32x4 acc[8][2]){
  #pragma unroll
  for (int kk = 0; kk < 4; ++kk){
    short8 b0 = *(const short8*)(Xw + l15*LDSPAD + kk*32 + q*8);
    short8 b1 = *(const short8*)(Xw + (16 + l15)*LDSPAD + kk*32 + q*8);
    #pragma unroll
    for (int mt = 0; mt < 8; ++mt){
      short8 a = *(const short8*)(W + (size_t)(mt*16 + l15)*COUT + kk*32 + q*8);
      acc[mt][0] = MFMA16(a, b0, acc[mt][0]);
      acc[mt][1] = MFMA16(a, b1, acc[mt][1]);
    }
  }
}

// y1 = relu(bn1(W1@X)); out = relu(bn2(W2@y1) + resid). Leaves post-relu f32 in acc.
__device__ __forceinline__ void res_block(const u16* __restrict__ W1, const u16* __restrict__ W2,
    const float* __restrict__ bn1, const float* __restrict__ bn2,
    u16* __restrict__ Xw, int q, int l15, u32 resid[8][2][2], f32x4 acc[8][2], bool writeback){
  zero_acc(acc);
  conv_step(W1, Xw, q, l15, acc);
  #pragma unroll
  for (int mt = 0; mt < 8; ++mt){
    f32x4 sc = *(const f32x4*)(bn1 + mt*16 + q*4);
    f32x4 bi = *(const f32x4*)(bn1 + 128 + mt*16 + q*4);
    #pragma unroll
    for (int nt = 0; nt < 2; ++nt){
      float y0 = fmaxf(fmaf(acc[mt][nt][0], sc[0], bi[0]), 0.f);
      float y1 = fmaxf(fmaf(acc[mt][nt][1], sc[1], bi[1]), 0.f);
      float y2 = fmaxf(fmaf(acc[mt][nt][2], sc[2], bi[2]), 0.f);
      float y3 = fmaxf(fmaf(acc[mt][nt][3], sc[3], bi[3]), 0.f);
      *(uint2*)(Xw + (nt*16 + l15)*LDSPAD + mt*16 + q*4) = make_uint2(pack2bf(y0,y1), pack2bf(y2,y3));
    }
  }
  __syncthreads();
  zero_acc(acc);
  conv_step(W2, Xw, q, l15, acc);
  #pragma unroll
  for (int mt = 0; mt < 8; ++mt){
    f32x4 sc = *(const f32x4*)(bn2 + mt*16 + q*4);
    f32x4 bi = *(const f32x4*)(bn2 + 128 + mt*16 + q*4);
    #pragma unroll
    for (int nt = 0; nt < 2; ++nt){
      float r0 = bf2f((u16)(resid[mt][nt][0] & 0xFFFFu));
      float r1 = bf2f((u16)(resid[mt][nt][0] >> 16));
      float r2 = bf2f((u16)(resid[mt][nt][1] & 0xFFFFu));
      float r3 = bf2f((u16)(resid[mt][nt][1] >> 16));
      float y0 = fmaxf(fmaf(acc[mt][nt][0], sc[0], bi[0]) + r0, 0.f);
      float y1 = fmaxf(fmaf(acc[mt][nt][1], sc[1], bi[1]) + r1, 0.f);
      float y2 = fmaxf(fmaf(acc[mt][nt][2], sc[2], bi[2]) + r2, 0.f);
      float y3 = fmaxf(fmaf(acc[mt][nt][3], sc[3], bi[3]) + r3, 0.f);
      acc[mt][nt][0] = y0; acc[mt][nt][1] = y1; acc[mt][nt][2] = y2; acc[mt][nt][3] = y3;
      if (writeback){
        u32 p0 = pack2bf(y0,y1), p1 = pack2bf(y2,y3);
        resid[mt][nt][0] = p0; resid[mt][nt][1] = p1;
        *(uint2*)(Xw + (nt*16 + l15)*LDSPAD + mt*16 + q*4) = make_uint2(p0, p1);
      }
    }
  }
  if (writeback) __syncthreads();
}

// ---------------------------------------------------------------------------
// mid: gather(knn, f32 feat -> bf16) -> te conv -> 2 pre res-blocks -> maxpool.
// One wave per center; 4 waves/block. Output x_mid[g][128] bf16 (ws).
// ---------------------------------------------------------------------------
__global__ __launch_bounds__(256) void mid_kernel(const float* __restrict__ feat,
    const u16* __restrict__ te_w, const u16* __restrict__ pre_w1, const u16* __restrict__ pre_w2,
    const float* __restrict__ bns, const int* __restrict__ fps_idx, const int* __restrict__ knn,
    u16* __restrict__ x_mid){
  __shared__ __align__(16) u16 X[4][32*LDSPAD];
  __shared__ __align__(16) float scr[4][128];
  const int wid = threadIdx.x >> 6, lane = threadIdx.x & 63;
  const int q = lane >> 4, l15 = lane & 15;
  const int g = blockIdx.x*4 + wid;
  const int b = g >> 11;
  const float* fb = feat + (size_t)b * N_ * CIN;
  u16* Xw = X[wid];

  const int ctr = fps_idx[g] & (N_ - 1);
  const int* kg = knn + (size_t)g * K_;
  #pragma unroll
  for (int it = 0; it < 4; ++it){
    int lidx = it*64 + lane;
    int col = lidx >> 3, kq = lidx & 7;           // col<32, 8-ch chunk kq<8
    int nb = kg[col] & (N_ - 1);
    f32x4 a0 = *(const f32x4*)(fb + (size_t)nb*CIN + kq*8);
    f32x4 a1 = *(const f32x4*)(fb + (size_t)nb*CIN + kq*8 + 4);
    *(uint2*)(Xw + col*LDSPAD + kq*8)     = make_uint2(pack2bf(a0[0],a0[1]), pack2bf(a0[2],a0[3]));
    *(uint2*)(Xw + col*LDSPAD + kq*8 + 4) = make_uint2(pack2bf(a1[0],a1[1]), pack2bf(a1[2],a1[3]));
    f32x4 c0 = *(const f32x4*)(fb + (size_t)ctr*CIN + kq*8);
    f32x4 c1 = *(const f32x4*)(fb + (size_t)ctr*CIN + kq*8 + 4);
    *(uint2*)(Xw + col*LDSPAD + 64 + kq*8)     = make_uint2(pack2bf(c0[0],c0[1]), pack2bf(c0[2],c0[3]));
    *(uint2*)(Xw + col*LDSPAD + 64 + kq*8 + 4) = make_uint2(pack2bf(c1[0],c1[1]), pack2bf(c1[2],c1[3]));
  }
  __syncthreads();

  f32x4 acc[8][2];
  u32 resid[8][2][2];
  zero_acc(acc);
  conv_step(te_w, Xw, q, l15, acc);
  #pragma unroll
  for (int mt = 0; mt < 8; ++mt){
    f32x4 sc = *(const f32x4*)(bns + mt*16 + q*4);
    f32x4 bi = *(const f32x4*)(bns + 128 + mt*16 + q*4);
    #pragma unroll
    for (int nt = 0; nt < 2; ++nt){
      float y0 = fmaxf(fmaf(acc[mt][nt][0], sc[0], bi[0]), 0.f);
      float y1 = fmaxf(fmaf(acc[mt][nt][1], sc[1], bi[1]), 0.f);
      float y2 = fmaxf(fmaf(acc[mt][nt][2], sc[2], bi[2]), 0.f);
      float y3 = fmaxf(fmaf(acc[mt][nt][3], sc[3], bi[3]), 0.f);
      u32 p0 = pack2bf(y0,y1), p1 = pack2bf(y2,y3);
      resid[mt][nt][0] = p0; resid[mt][nt][1] = p1;
      *(uint2*)(Xw + (nt*16 + l15)*LDSPAD + mt*16 + q*4) = make_uint2(p0, p1);
    }
  }
  __syncthreads();

  res_block(pre_w1,             pre_w2,             bns + 256, bns + 512,  Xw, q, l15, resid, acc, true);
  res_block(pre_w1 + COUT*COUT, pre_w2 + COUT*COUT, bns + 768, bns + 1024, Xw, q, l15, resid, acc, false);

  // maxpool over 32 cols (nt pair + butterfly over low-4 lane bits)
  float mx[8][4];
  #pragma unroll
  for (int mt = 0; mt < 8; ++mt)
    #pragma unroll
    for (int r = 0; r < 4; ++r){
      float m0 = fmaxf(acc[mt][0][r], acc[mt][1][r]);
      #pragma unroll
      for (int off = 1; off < 16; off <<= 1) m0 = fmaxf(m0, __shfl_xor(m0, off));
      mx[mt][r] = m0;
    }
  if (l15 == 0){
    #pragma unroll
    for (int mt = 0; mt < 8; ++mt){
      f32x4 vv; vv[0] = mx[mt][0]; vv[1] = mx[mt][1]; vv[2] = mx[mt][2]; vv[3] = mx[mt][3];
      *(f32x4*)(scr[wid] + mt*16 + q*4) = vv;
    }
  }
  __syncthreads();
  float v0 = scr[wid][lane*2], v1 = scr[wid][lane*2 + 1];
  *(u32*)(x_mid + (size_t)g*COUT + lane*2) = pack2bf(v0, v1);
}

// ---------------------------------------------------------------------------
// pos: 2 res-blocks over (B,128,2048); one wave per 32 columns. f32 out.
// ---------------------------------------------------------------------------
__global__ __launch_bounds__(256) void pos_kernel(const u16* __restrict__ x_mid,
    const u16* __restrict__ pos_w1, const u16* __restrict__ pos_w2,
    const float* __restrict__ bns, float* __restrict__ out_x){
  __shared__ __align__(16) u16 X[4][32*LDSPAD];
  const int wid = threadIdx.x >> 6, lane = threadIdx.x & 63;
  const int q = lane >> 4, l15 = lane & 15;
  const int g = blockIdx.x*4 + wid;            // 0..511
  const int gc0 = g * 32;
  const int b = gc0 >> 11, s0 = gc0 & 2047;
  u16* Xw = X[wid];
  #pragma unroll
  for (int it = 0; it < 8; ++it){
    int lidx = it*64 + lane;
    int col = lidx >> 4, kq = lidx & 15;
    uint4 v = *(const uint4*)(x_mid + (size_t)(gc0 + col)*COUT + kq*8);
    *(uint4*)(Xw + col*LDSPAD + kq*8) = v;
  }
  __syncthreads();
  u32 resid[8][2][2];
  #pragma unroll
  for (int mt = 0; mt < 8; ++mt)
    #pragma unroll
    for (int nt = 0; nt < 2; ++nt){
      uint2 rr = *(const uint2*)(Xw + (nt*16 + l15)*LDSPAD + mt*16 + q*4);
      resid[mt][nt][0] = rr.x; resid[mt][nt][1] = rr.y;
    }
  f32x4 acc[8][2];
  res_block(pos_w1,             pos_w2,             bns + 1280, bns + 1536, Xw, q, l15, resid, acc, true);
  res_block(pos_w1 + COUT*COUT, pos_w2 + COUT*COUT, bns + 1792, bns + 2048, Xw, q, l15, resid, acc, false);
  #pragma unroll
  for (int mt = 0; mt < 8; ++mt)
    #pragma unroll
    for (int nt = 0; nt < 2; ++nt)
      #pragma unroll
      for (int r = 0; r < 4; ++r){
        int row = mt*16 + q*4 + r;
        int colx = s0 + nt*16 + l15;
        out_x[(size_t)(b*COUT + row)*NS + colx] = acc[mt][nt][r];
      }
}

// ---------------------------------------------------------------------------
extern "C" void kernel_launch(void* const* d_in, const int* in_sizes, int n_in,
                              void* d_out, int out_size, void* d_ws, size_t ws_size,
                              hipStream_t stream){
  (void)in_sizes; (void)n_in; (void)out_size; (void)ws_size;
  const float* xyz    = (const float*)d_in[0];
  const float* feat   = (const float*)d_in[1];

  // ws layout (16B aligned, ~6.4 MB total):
  char* ws = (char*)d_ws;
  float* bns     = (float*)ws;                          // 16 KiB (9.2 used)
  u16*   wbf     = (u16*)(ws + 16384);                  // 288 KiB bf16 weights
  int*   fps_idx = (int*)(ws + 16384 + 294912);         // 64 KiB
  int*   knn     = (int*)(ws + 16384 + 294912 + 65536); // 2 MiB
  u16*   x_mid   = (u16*)(ws + 16384 + 294912 + 65536 + 2097152); // 4 MiB
  // FPS cross-block flags ALIAS the x_mid region (512 KiB of the 4 MiB):
  // fps (reader/writer) finishes before mid_kernel writes x_mid. Write-once
  // per (block,step); cleared every launch by fps_flags_clear_kernel.
  u64*   fflags  = (u64*)x_mid;                         // 8*4*2048*8 = 512 KiB
  float* out_xyz = (float*)d_out;                       // (8,2048,3) f32
  float* out_x   = (float*)d_out + B_*NS*3;             // (8,128,2048) f32

  // bf16 weight staging: te(16384) pre_w1(32768) pre_w2(32768) pos_w1(32768) pos_w2(32768)
  u16* te_w   = wbf;
  u16* pre_w1 = wbf + 16384;
  u16* pre_w2 = wbf + 49152;
  u16* pos_w1 = wbf + 81920;
  u16* pos_w2 = wbf + 114688;
  wcvt_kernel<<<64,  256, 0, stream>>>((const float*)d_in[2],  te_w,   16384);
  wcvt_kernel<<<128, 256, 0, stream>>>((const float*)d_in[7],  pre_w1, 32768);
  wcvt_kernel<<<128, 256, 0, stream>>>((const float*)d_in[8],  pre_w2, 32768);
  wcvt_kernel<<<128, 256, 0, stream>>>((const float*)d_in[17], pos_w1, 32768);
  wcvt_kernel<<<128, 256, 0, stream>>>((const float*)d_in[18], pos_w2, 32768);
  fps_flags_clear_kernel<<<128, 256, 0, stream>>>((uint4*)fflags, (B_*FPS_NBLK*NS*8)/16);

  // dict order: te_g/b/m/v = 3..6 ; pre: w1,w2,g1,g2,b1,b2,m1,m2,v1,v2 = 7..16 ; pos = 17..26
  BnPtrs bp;
  const int gi[9] = {3, 9, 10, 9, 10, 19, 20, 19, 20};
  const int bbi[9]= {4, 11,12, 11,12, 21, 22, 21, 22};
  const int mi[9] = {5, 13,14, 13,14, 23, 24, 23, 24};
  const int vi[9] = {6, 15,16, 15,16, 25, 26, 25, 26};
  const int of[9] = {0, 0, 0, 128,128, 0, 0, 128,128};
  for (int k = 0; k < 9; ++k){
    bp.g[k] = (const float*)d_in[gi[k]]  + of[k];
    bp.b[k] = (const float*)d_in[bbi[k]] + of[k];
    bp.m[k] = (const float*)d_in[mi[k]]  + of[k];
    bp.v[k] = (const float*)d_in[vi[k]]  + of[k];
  }

  bn_pre_kernel<<<9, 128, 0, stream>>>(bp, bns);
  fps_kernel<<<B_*FPS_NBLK, 512, 0, stream>>>(xyz, fps_idx, fflags);
  knn_kernel<<<(B_*NS)/4, 256, 0, stream>>>(xyz, fps_idx, knn, out_xyz);
  mid_kernel<<<(B_*NS)/4, 256, 0, stream>>>(feat, te_w, pre_w1, pre_w2, bns, fps_idx, knn, x_mid);
  pos_kernel<<<(B_*NS/K_)/4, 256, 0, stream>>>(x_mid, pos_w1, pos_w2, bns, out_x);
}

// Round 2
// 3196.118 us; speedup vs baseline: 1.0835x; 1.0835x over previous
//
#include <hip/hip_runtime.h>

typedef unsigned short u16;
typedef unsigned int   u32;
typedef unsigned long long u64;

#define B_    8
#define N_    8192
#define CIN   64
#define COUT  128
#define NS    2048
#define K_    32
#define LDSPAD 136   // 128 + 8 bf16: breaks bank conflicts on column stride

typedef __attribute__((ext_vector_type(8))) short short8;
typedef __attribute__((ext_vector_type(4))) float f32x4;

#define MFMA16(a,b,c) __builtin_amdgcn_mfma_f32_16x16x32_bf16(a,b,c,0,0,0)

__device__ __forceinline__ u16 f2bf(float f){
  u32 u = __float_as_uint(f);
  return (u16)((u + 0x7FFFu + ((u >> 16) & 1u)) >> 16);   // RNE, finite values only
}
__device__ __forceinline__ float bf2f(u16 h){ u32 u = ((u32)h) << 16; return __uint_as_float(u); }
__device__ __forceinline__ u32 pack2bf(float lo, float hi){ return (u32)f2bf(lo) | ((u32)f2bf(hi) << 16); }

// ---------------------------------------------------------------------------
// Weight f32 -> bf16 conversion (one-time prep into ws)
// ---------------------------------------------------------------------------
__global__ void wcvt_kernel(const float* __restrict__ s, u16* __restrict__ d, int n){
  int i = blockIdx.x * 256 + threadIdx.x;
  if (i < n) d[i] = f2bf(s[i]);
}

// fps_idx -> -1 sentinel, done flags -> 0 (per launch; graph replay reuses ws)
__global__ void clear_kernel(int* __restrict__ fps_idx, u32* __restrict__ done){
  int i = blockIdx.x * 256 + threadIdx.x;
  if (i < B_*NS){ fps_idx[i] = -1; done[i] = 0u; }
}

// ---------------------------------------------------------------------------
// BN constants: scale = g/sqrt(v+eps), bias = b - m*scale  (all f32 inputs)
// set order: 0=te, 1/2=pre0.bn1/bn2, 3/4=pre1.bn1/bn2, 5/6=pos0, 7/8=pos1
// ---------------------------------------------------------------------------
struct BnPtrs { const float* g[9]; const float* b[9]; const float* m[9]; const float* v[9]; };

__global__ void bn_pre_kernel(BnPtrs p, float* __restrict__ bns){
  int set = blockIdx.x, c = threadIdx.x;
  float sc = p.g[set][c] / sqrtf(p.v[set][c] + 1e-5f);
  bns[set*256 + c]       = sc;
  bns[set*256 + 128 + c] = p.b[set][c] - p.m[set][c] * sc;
}

// ---------------------------------------------------------------------------
// MEGA-KERNEL layout. Round-1 lesson: cross-CU exchange per FPS step costs
// more than the VALU it saves (agent-scope round trips ~600+cyc). So FPS
// stays single-CU-per-batch (v5 structure, 2215us, known-correct), and we
// instead use the 248 idle CUs: knn+mid consume fps_idx as a STREAM
// (center g=b*2048+s is final after step s), pos consumes x_mid as a stream.
//   blocks 0..7        : fps (one batch each; 1 block/CU via 98KB LDS union,
//                        so consumers NEVER co-tenant the fps CUs)
//   blocks 8..2055     : knn+mid fused, 8 centers/block (1 wave/center);
//                        spin on fps_idx[g] (relaxed agent load + s_sleep;
//                        index VALUE is the payload - no fence needed)
//   blocks 2056..2119  : pos, 8 col-groups/block; spin on done[g] flags,
//                        acquire fence before reading x_mid
// knn result stays in registers (wave-local) and is handed to mid via shfl
// - the 2MB knn buffer is gone. Producer publishes with release-agent store.
// Deadlock-free: blocks dispatched in id order -> fps blocks resident first;
// consumers' spins depend only on fps; pos depends only on consumers.
// ---------------------------------------------------------------------------
struct ShFps {
  __align__(16) f32x4 PX4[4*512];
  __align__(16) f32x4 PY4[4*512];
  __align__(16) f32x4 PZ4[4*512];
  u64  kArr[2][8];
  float xA[2][8], yA[2][8], zA[2][8];
};
struct ShMid {
  __align__(16) u16 X[8][32*LDSPAD];
  __align__(16) float scr[8][128];
};
struct ShPos {
  __align__(16) u16 X[8][32*LDSPAD];
};
union ShAll { ShFps f; ShMid m; ShPos p; };   // 98.6 KB -> 1 block/CU

// ---------------------------------------------------------------------------
// FPS v5 (verbatim from the 2965us baseline): DPP-based reduce, serial-latency
// bound on one CU per batch. Exact f32 (contract off); tie -> lowest index.
// ---------------------------------------------------------------------------
#define DPP_UMAX(x, ctrl) { \
  u32 o = (u32)__builtin_amdgcn_update_dpp((int)(x), (int)(x), ctrl, 0xf, 0xf, false); \
  x = (o > x) ? o : x; }

__device__ __forceinline__ u32 wave_umax63(u32 x){
  DPP_UMAX(x, 0x111)  // row_shr:1
  DPP_UMAX(x, 0x112)  // row_shr:2
  DPP_UMAX(x, 0x114)  // row_shr:4
  DPP_UMAX(x, 0x118)  // row_shr:8
  DPP_UMAX(x, 0x142)  // row_bcast:15
  DPP_UMAX(x, 0x143)  // row_bcast:31
  return (u32)__builtin_amdgcn_readlane((int)x, 63);
}

#define FPS_STEP4(j) { \
  f32x4 xv = PX4[j*512 + t]; \
  f32x4 yv = PY4[j*512 + t]; \
  f32x4 zv = PZ4[j*512 + t]; \
  FPS_ONE(j,0) FPS_ONE(j,1) FPS_ONE(j,2) FPS_ONE(j,3) }

#define FPS_ONE(j,i) { \
  float dx = xv[i] - lx; \
  float dy = yv[i] - ly; \
  float dz = zv[i] - lz; \
  float t0 = dx*dx; \
  float t1 = dy*dy; \
  float t2 = dz*dz; \
  float dd = (t0 + t1) + t2;  /* same assoc as np.sum axis=-1 */ \
  float nd = fminf(D##j##i, dd); \
  D##j##i = nd; \
  u32 nb = __float_as_uint(nd); \
  tb##j = (nb > tb##j) ? nb : tb##j; }

#define FPS_KMIN(j,i) \
  kk = (__float_as_uint(D##j##i) == wmax && (4*j+i) < kk) ? (4*j+i) : kk;

__device__ void fps_path(const float* __restrict__ xyz, int* __restrict__ fps_idx,
                         ShFps& S, int b, int t){
  #pragma clang fp contract(off)
  const int lane = t & 63, wv = t >> 6;
  const float* xb = xyz + (size_t)b * N_ * 3;
  f32x4* PX4 = S.PX4; f32x4* PY4 = S.PY4; f32x4* PZ4 = S.PZ4;
  const int base = t * 16;
  #pragma unroll
  for (int j = 0; j < 4; ++j){                  // one-time transpose stage-in
    f32x4 xv, yv, zv;
    #pragma unroll
    for (int i = 0; i < 4; ++i){
      const int p = base + 4*j + i;
      xv[i] = xb[p*3 + 0];
      yv[i] = xb[p*3 + 1];
      zv[i] = xb[p*3 + 2];
    }
    PX4[j*512 + t] = xv; PY4[j*512 + t] = yv; PZ4[j*512 + t] = zv;
  }
  if (t == 0)
    __hip_atomic_store(fps_idx + b*NS, 0, __ATOMIC_RELEASE, __HIP_MEMORY_SCOPE_AGENT);
  __syncthreads();
  float D00=1e10f,D01=1e10f,D02=1e10f,D03=1e10f;
  float D10=1e10f,D11=1e10f,D12=1e10f,D13=1e10f;
  float D20=1e10f,D21=1e10f,D22=1e10f,D23=1e10f;
  float D30=1e10f,D31=1e10f,D32=1e10f,D33=1e10f;
  const float* PXs = (const float*)PX4;
  const float* PYs = (const float*)PY4;
  const float* PZs = (const float*)PZ4;
  float lx = PXs[0], ly = PYs[0], lz = PZs[0];  // point 0 is the seed
  for (int s = 0; s < NS - 1; ++s){
    u32 tb0 = 0, tb1 = 0, tb2 = 0, tb3 = 0;     // dist >= 0 -> bits valid for umax
    FPS_STEP4(0) FPS_STEP4(1) FPS_STEP4(2) FPS_STEP4(3)
    u32 ta = (tb0 > tb1) ? tb0 : tb1;
    u32 tc = (tb2 > tb3) ? tb2 : tb3;
    u32 tbm = (ta > tc) ? ta : tc;              // per-thread max (4+2 tree)
    const u32 wmax = wave_umax63(tbm);          // 6 VALU DPP ops + readlane
    const u64 mask = __ballot(tbm == wmax);
    const int fl = __ffsll((long long)mask) - 1;   // lowest lane = lowest index
    const int sl = s & 1;
    if (lane == fl){
      int kk = 64;
      FPS_KMIN(0,0) FPS_KMIN(0,1) FPS_KMIN(0,2) FPS_KMIN(0,3)
      FPS_KMIN(1,0) FPS_KMIN(1,1) FPS_KMIN(1,2) FPS_KMIN(1,3)
      FPS_KMIN(2,0) FPS_KMIN(2,1) FPS_KMIN(2,2) FPS_KMIN(2,3)
      FPS_KMIN(3,0) FPS_KMIN(3,1) FPS_KMIN(3,2) FPS_KMIN(3,3)
      const int pi = base + kk;                  // first max index in this wave
      S.kArr[sl][wv] = ((u64)wmax << 13) | (u64)(8191 - pi);
      const int li = ((kk >> 2)*512 + t)*4 + (kk & 3);
      S.xA[sl][wv] = PXs[li]; S.yA[sl][wv] = PYs[li]; S.zA[sl][wv] = PZs[li];
    }
    __syncthreads();
    // parallel load of all 8 records, then cndmask select (no dependent load)
    u64 win = S.kArr[sl][0];
    float cx = S.xA[sl][0], cy = S.yA[sl][0], cz = S.zA[sl][0];
    #pragma unroll
    for (int w = 1; w < 8; ++w){
      u64 o = S.kArr[sl][w];
      float ox = S.xA[sl][w], oy = S.yA[sl][w], oz = S.zA[sl][w];
      bool c = o > win;
      win = c ? o : win; cx = c ? ox : cx; cy = c ? oy : cy; cz = c ? oz : cz;
    }
    lx = cx; ly = cy; lz = cz;
    if (t == 0)
      __hip_atomic_store(fps_idx + b*NS + s + 1, 8191 - (int)(win & 0x1FFFull),
                         __ATOMIC_RELEASE, __HIP_MEMORY_SCOPE_AGENT);
  }
}

// ---------------------------------------------------------------------------
// Conv stack helpers (unchanged, m89-verified MFMA layouts).
// ---------------------------------------------------------------------------
__device__ __forceinline__ void zero_acc(f32x4 acc[8][2]){
  #pragma unroll
  for (int mt = 0; mt < 8; ++mt)
    #pragma unroll
    for (int nt = 0; nt < 2; ++nt){
      acc[mt][nt][0] = 0.f; acc[mt][nt][1] = 0.f; acc[mt][nt][2] = 0.f; acc[mt][nt][3] = 0.f;
    }
}

__device__ __forceinline__ void conv_step(const u16* __restrict__ W, const u16* __restrict__ Xw,
                                          int q, int l15, f32x4 acc[8][2]){
  #pragma unroll
  for (int kk = 0; kk < 4; ++kk){
    short8 b0 = *(const short8*)(Xw + l15*LDSPAD + kk*32 + q*8);
    short8 b1 = *(const short8*)(Xw + (16 + l15)*LDSPAD + kk*32 + q*8);
    #pragma unroll
    for (int mt = 0; mt < 8; ++mt){
      short8 a = *(const short8*)(W + (size_t)(mt*16 + l15)*COUT + kk*32 + q*8);
      acc[mt][0] = MFMA16(a, b0, acc[mt][0]);
      acc[mt][1] = MFMA16(a, b1, acc[mt][1]);
    }
  }
}

// y1 = relu(bn1(W1@X)); out = relu(bn2(W2@y1) + resid). Leaves post-relu f32 in acc.
__device__ __forceinline__ void res_block(const u16* __restrict__ W1, const u16* __restrict__ W2,
    const float* __restrict__ bn1, const float* __restrict__ bn2,
    u16* __restrict__ Xw, int q, int l15, u32 resid[8][2][2], f32x4 acc[8][2], bool writeback){
  zero_acc(acc);
  conv_step(W1, Xw, q, l15, acc);
  #pragma unroll
  for (int mt = 0; mt < 8; ++mt){
    f32x4 sc = *(const f32x4*)(bn1 + mt*16 + q*4);
    f32x4 bi = *(const f32x4*)(bn1 + 128 + mt*16 + q*4);
    #pragma unroll
    for (int nt = 0; nt < 2; ++nt){
      float y0 = fmaxf(fmaf(acc[mt][nt][0], sc[0], bi[0]), 0.f);
      float y1 = fmaxf(fmaf(acc[mt][nt][1], sc[1], bi[1]), 0.f);
      float y2 = fmaxf(fmaf(acc[mt][nt][2], sc[2], bi[2]), 0.f);
      float y3 = fmaxf(fmaf(acc[mt][nt][3], sc[3], bi[3]), 0.f);
      *(uint2*)(Xw + (nt*16 + l15)*LDSPAD + mt*16 + q*4) = make_uint2(pack2bf(y0,y1), pack2bf(y2,y3));
    }
  }
  __syncthreads();
  zero_acc(acc);
  conv_step(W2, Xw, q, l15, acc);
  #pragma unroll
  for (int mt = 0; mt < 8; ++mt){
    f32x4 sc = *(const f32x4*)(bn2 + mt*16 + q*4);
    f32x4 bi = *(const f32x4*)(bn2 + 128 + mt*16 + q*4);
    #pragma unroll
    for (int nt = 0; nt < 2; ++nt){
      float r0 = bf2f((u16)(resid[mt][nt][0] & 0xFFFFu));
      float r1 = bf2f((u16)(resid[mt][nt][0] >> 16));
      float r2 = bf2f((u16)(resid[mt][nt][1] & 0xFFFFu));
      float r3 = bf2f((u16)(resid[mt][nt][1] >> 16));
      float y0 = fmaxf(fmaf(acc[mt][nt][0], sc[0], bi[0]) + r0, 0.f);
      float y1 = fmaxf(fmaf(acc[mt][nt][1], sc[1], bi[1]) + r1, 0.f);
      float y2 = fmaxf(fmaf(acc[mt][nt][2], sc[2], bi[2]) + r2, 0.f);
      float y3 = fmaxf(fmaf(acc[mt][nt][3], sc[3], bi[3]) + r3, 0.f);
      acc[mt][nt][0] = y0; acc[mt][nt][1] = y1; acc[mt][nt][2] = y2; acc[mt][nt][3] = y3;
      if (writeback){
        u32 p0 = pack2bf(y0,y1), p1 = pack2bf(y2,y3);
        resid[mt][nt][0] = p0; resid[mt][nt][1] = p1;
        *(uint2*)(Xw + (nt*16 + l15)*LDSPAD + mt*16 + q*4) = make_uint2(p0, p1);
      }
    }
  }
  if (writeback) __syncthreads();
}

// ---------------------------------------------------------------------------
// knn (register-resident result) + mid, one wave per center. Spins on
// fps_idx[g]; the index value itself is the payload (no fence needed).
// ---------------------------------------------------------------------------
__device__ void knnmid_path(const float* __restrict__ xyz, const float* __restrict__ feat,
    const u16* __restrict__ te_w, const u16* __restrict__ pre_w1, const u16* __restrict__ pre_w2,
    const float* __restrict__ bns, int* __restrict__ fps_idx,
    u16* __restrict__ x_mid, u32* __restrict__ done, float* __restrict__ out_xyz,
    u16* __restrict__ Xw, float* __restrict__ scrw, int g, int lane){
  #pragma clang fp contract(off)
  const int b = g >> 11;
  const float* xb = xyz + (size_t)b * N_ * 3;

  int raw;
  for (;;){
    raw = __hip_atomic_load(fps_idx + g, __ATOMIC_RELAXED, __HIP_MEMORY_SCOPE_AGENT);
    if (raw >= 0) break;
    __builtin_amdgcn_s_sleep(4);
  }
  const int ci = raw & (N_ - 1);                // clamp: fault-proof
  const float cx = xb[ci*3], cy = xb[ci*3+1], cz = xb[ci*3+2];
  if (lane < 3) out_xyz[g*3 + lane] = xb[ci*3 + lane];

  // --- knn: sorted 64-slot lane list, threshold slot 31 (exact f32 + lex tie)
  float rd = __uint_as_float(0x7F800000u); int ri = 0x7FFFFFFF;
  float r31d = rd; int r31i = ri;
  for (int c = 0; c < N_/64; ++c){
    const int pid = c*64 + lane;
    float dx = xb[pid*3]   - cx;
    float dy = xb[pid*3+1] - cy;
    float dz = xb[pid*3+2] - cz;
    float t0 = dx*dx, t1 = dy*dy, t2 = dz*dz;
    float d2 = (t0 + t1) + t2;
    u64 m = __ballot((d2 < r31d) || (d2 == r31d && pid < r31i));
    while (m){
      int l = __ffsll((long long)m) - 1; m &= m - 1;
      float v = __shfl(d2, l); int vi = c*64 + l;
      if (!((v < r31d) || (v == r31d && vi < r31i))) continue;  // re-check vs updated threshold
      bool lt = (rd < v) || (rd == v && ri < vi);
      int pos = __popcll(__ballot(lt));
      float prd = __shfl_up(rd, 1); int pri = __shfl_up(ri, 1);
      if (lane == pos){ rd = v; ri = vi; }
      else if (lane > pos){ rd = prd; ri = pri; }
      r31d = __shfl(rd, 31); r31i = __shfl(ri, 31);
    }
  }
  // neighbor k (k<32) lives in lane k's ri - handed to mid via shfl below.

  // --- mid: gather -> te conv -> 2 pre res-blocks -> maxpool
  const int q = lane >> 4, l15 = lane & 15;
  const float* fb = feat + (size_t)b * N_ * CIN;
  #pragma unroll
  for (int it = 0; it < 4; ++it){
    int lidx = it*64 + lane;
    int kq = lidx & 7;                            // 8-ch chunk
    int col = it*8 + (lane >> 3);                 // col<32
    int nb = __shfl(ri, col) & (N_ - 1);
    f32x4 a0 = *(const f32x4*)(fb + (size_t)nb*CIN + kq*8);
    f32x4 a1 = *(const f32x4*)(fb + (size_t)nb*CIN + kq*8 + 4);
    *(uint2*)(Xw + col*LDSPAD + kq*8)     = make_uint2(pack2bf(a0[0],a0[1]), pack2bf(a0[2],a0[3]));
    *(uint2*)(Xw + col*LDSPAD + kq*8 + 4) = make_uint2(pack2bf(a1[0],a1[1]), pack2bf(a1[2],a1[3]));
    f32x4 c0 = *(const f32x4*)(fb + (size_t)ci*CIN + kq*8);
    f32x4 c1 = *(const f32x4*)(fb + (size_t)ci*CIN + kq*8 + 4);
    *(uint2*)(Xw + col*LDSPAD + 64 + kq*8)     = make_uint2(pack2bf(c0[0],c0[1]), pack2bf(c0[2],c0[3]));
    *(uint2*)(Xw + col*LDSPAD + 64 + kq*8 + 4) = make_uint2(pack2bf(c1[0],c1[1]), pack2bf(c1[2],c1[3]));
  }
  __syncthreads();

  f32x4 acc[8][2];
  u32 resid[8][2][2];
  zero_acc(acc);
  conv_step(te_w, Xw, q, l15, acc);
  #pragma unroll
  for (int mt = 0; mt < 8; ++mt){
    f32x4 sc = *(const f32x4*)(bns + mt*16 + q*4);
    f32x4 bi = *(const f32x4*)(bns + 128 + mt*16 + q*4);
    #pragma unroll
    for (int nt = 0; nt < 2; ++nt){
      float y0 = fmaxf(fmaf(acc[mt][nt][0], sc[0], bi[0]), 0.f);
      float y1 = fmaxf(fmaf(acc[mt][nt][1], sc[1], bi[1]), 0.f);
      float y2 = fmaxf(fmaf(acc[mt][nt][2], sc[2], bi[2]), 0.f);
      float y3 = fmaxf(fmaf(acc[mt][nt][3], sc[3], bi[3]), 0.f);
      u32 p0 = pack2bf(y0,y1), p1 = pack2bf(y2,y3);
      resid[mt][nt][0] = p0; resid[mt][nt][1] = p1;
      *(uint2*)(Xw + (nt*16 + l15)*LDSPAD + mt*16 + q*4) = make_uint2(p0, p1);
    }
  }
  __syncthreads();

  res_block(pre_w1,             pre_w2,             bns + 256, bns + 512,  Xw, q, l15, resid, acc, true);
  res_block(pre_w1 + COUT*COUT, pre_w2 + COUT*COUT, bns + 768, bns + 1024, Xw, q, l15, resid, acc, false);

  // maxpool over 32 cols (nt pair + butterfly over low-4 lane bits)
  float mx[8][4];
  #pragma unroll
  for (int mt = 0; mt < 8; ++mt)
    #pragma unroll
    for (int r = 0; r < 4; ++r){
      float m0 = fmaxf(acc[mt][0][r], acc[mt][1][r]);
      #pragma unroll
      for (int off = 1; off < 16; off <<= 1) m0 = fmaxf(m0, __shfl_xor(m0, off));
      mx[mt][r] = m0;
    }
  if (l15 == 0){
    #pragma unroll
    for (int mt = 0; mt < 8; ++mt){
      f32x4 vv; vv[0] = mx[mt][0]; vv[1] = mx[mt][1]; vv[2] = mx[mt][2]; vv[3] = mx[mt][3];
      *(f32x4*)(scrw + mt*16 + q*4) = vv;
    }
  }
  __syncthreads();
  float v0 = scrw[lane*2], v1 = scrw[lane*2 + 1];
  *(u32*)(x_mid + (size_t)g*COUT + lane*2) = pack2bf(v0, v1);
  if (lane == 0)   // release: s_waitcnt is wave-level -> covers all lanes' stores
    __hip_atomic_store(done + g, 1u, __ATOMIC_RELEASE, __HIP_MEMORY_SCOPE_AGENT);
}

// ---------------------------------------------------------------------------
// pos: 2 res-blocks over (B,128,2048); one wave per 32 columns. Spins on the
// 32 done flags of its column group, acquire-fences, then reads x_mid.
// ---------------------------------------------------------------------------
__device__ void pos_path(const u16* __restrict__ x_mid,
    const u16* __restrict__ pos_w1, const u16* __restrict__ pos_w2,
    const float* __restrict__ bns, float* __restrict__ out_x,
    u32* __restrict__ done, u16* __restrict__ Xw, int g, int lane){
  const int q = lane >> 4, l15 = lane & 15;
  const int gc0 = g * 32;
  const int b = gc0 >> 11, s0 = gc0 & 2047;
  for (;;){
    u32 d = (lane < 32)
      ? __hip_atomic_load(done + gc0 + lane, __ATOMIC_RELAXED, __HIP_MEMORY_SCOPE_AGENT)
      : 1u;
    if (__all(d != 0)) break;
    __builtin_amdgcn_s_sleep(4);
  }
  __builtin_amdgcn_fence(__ATOMIC_ACQUIRE, "agent");
  #pragma unroll
  for (int it = 0; it < 8; ++it){
    int lidx = it*64 + lane;
    int col = lidx >> 4, kq = lidx & 15;
    uint4 v = *(const uint4*)(x_mid + (size_t)(gc0 + col)*COUT + kq*8);
    *(uint4*)(Xw + col*LDSPAD + kq*8) = v;
  }
  __syncthreads();
  u32 resid[8][2][2];
  #pragma unroll
  for (int mt = 0; mt < 8; ++mt)
    #pragma unroll
    for (int nt = 0; nt < 2; ++nt){
      uint2 rr = *(const uint2*)(Xw + (nt*16 + l15)*LDSPAD + mt*16 + q*4);
      resid[mt][nt][0] = rr.x; resid[mt][nt][1] = rr.y;
    }
  f32x4 acc[8][2];
  res_block(pos_w1,             pos_w2,             bns + 1280, bns + 1536, Xw, q, l15, resid, acc, true);
  res_block(pos_w1 + COUT*COUT, pos_w2 + COUT*COUT, bns + 1792, bns + 2048, Xw, q, l15, resid, acc, false);
  #pragma unroll
  for (int mt = 0; mt < 8; ++mt)
    #pragma unroll
    for (int nt = 0; nt < 2; ++nt)
      #pragma unroll
      for (int r = 0; r < 4; ++r){
        int row = mt*16 + q*4 + r;
        int colx = s0 + nt*16 + l15;
        out_x[(size_t)(b*COUT + row)*NS + colx] = acc[mt][nt][r];
      }
}

// ---------------------------------------------------------------------------
#define GRID_FPS    B_                 // 8
#define GRID_KM     (B_*NS/8)          // 2048 blocks x 8 waves = 16384 centers
#define GRID_POS    (B_*NS/K_/8)       // 64 blocks x 8 waves = 512 groups

__global__ __launch_bounds__(512) void mega_kernel(
    const float* __restrict__ xyz, const float* __restrict__ feat,
    const u16* __restrict__ te_w, const u16* __restrict__ pre_w1, const u16* __restrict__ pre_w2,
    const u16* __restrict__ pos_w1, const u16* __restrict__ pos_w2,
    const float* __restrict__ bns, int* __restrict__ fps_idx,
    u16* __restrict__ x_mid, u32* __restrict__ done,
    float* __restrict__ out_xyz, float* __restrict__ out_x){
  __shared__ ShAll sh;
  const int bid = blockIdx.x;
  const int t = threadIdx.x;
  const int wid = t >> 6, lane = t & 63;
  if (bid < GRID_FPS){
    fps_path(xyz, fps_idx, sh.f, bid, t);
  } else if (bid < GRID_FPS + GRID_KM){
    const int g = (bid - GRID_FPS)*8 + wid;
    knnmid_path(xyz, feat, te_w, pre_w1, pre_w2, bns, fps_idx, x_mid, done, out_xyz,
                sh.m.X[wid], sh.m.scr[wid], g, lane);
  } else {
    const int g = (bid - GRID_FPS - GRID_KM)*8 + wid;
    pos_path(x_mid, pos_w1, pos_w2, bns, out_x, done, sh.p.X[wid], g, lane);
  }
}

// ---------------------------------------------------------------------------
extern "C" void kernel_launch(void* const* d_in, const int* in_sizes, int n_in,
                              void* d_out, int out_size, void* d_ws, size_t ws_size,
                              hipStream_t stream){
  (void)in_sizes; (void)n_in; (void)out_size; (void)ws_size;
  const float* xyz    = (const float*)d_in[0];
  const float* feat   = (const float*)d_in[1];

  // ws layout (16B aligned, ~4.7 MB total):
  char* ws = (char*)d_ws;
  float* bns     = (float*)ws;                          // 16 KiB (9.2 used)
  u16*   wbf     = (u16*)(ws + 16384);                  // 288 KiB bf16 weights
  int*   fps_idx = (int*)(ws + 16384 + 294912);         // 64 KiB
  u32*   done    = (u32*)(ws + 16384 + 294912 + 65536); // 64 KiB
  u16*   x_mid   = (u16*)(ws + 16384 + 294912 + 65536 + 65536); // 4 MiB
  float* out_xyz = (float*)d_out;                       // (8,2048,3) f32
  float* out_x   = (float*)d_out + B_*NS*3;             // (8,128,2048) f32

  // bf16 weight staging: te(16384) pre_w1(32768) pre_w2(32768) pos_w1(32768) pos_w2(32768)
  u16* te_w   = wbf;
  u16* pre_w1 = wbf + 16384;
  u16* pre_w2 = wbf + 49152;
  u16* pos_w1 = wbf + 81920;
  u16* pos_w2 = wbf + 114688;
  wcvt_kernel<<<64,  256, 0, stream>>>((const float*)d_in[2],  te_w,   16384);
  wcvt_kernel<<<128, 256, 0, stream>>>((const float*)d_in[7],  pre_w1, 32768);
  wcvt_kernel<<<128, 256, 0, stream>>>((const float*)d_in[8],  pre_w2, 32768);
  wcvt_kernel<<<128, 256, 0, stream>>>((const float*)d_in[17], pos_w1, 32768);
  wcvt_kernel<<<128, 256, 0, stream>>>((const float*)d_in[18], pos_w2, 32768);
  clear_kernel<<<64, 256, 0, stream>>>(fps_idx, done);

  // dict order: te_g/b/m/v = 3..6 ; pre: w1,w2,g1,g2,b1,b2,m1,m2,v1,v2 = 7..16 ; pos = 17..26
  BnPtrs bp;
  const int gi[9] = {3, 9, 10, 9, 10, 19, 20, 19, 20};
  const int bbi[9]= {4, 11,12, 11,12, 21, 22, 21, 22};
  const int mi[9] = {5, 13,14, 13,14, 23, 24, 23, 24};
  const int vi[9] = {6, 15,16, 15,16, 25, 26, 25, 26};
  const int of[9] = {0, 0, 0, 128,128, 0, 0, 128,128};
  for (int k = 0; k < 9; ++k){
    bp.g[k] = (const float*)d_in[gi[k]]  + of[k];
    bp.b[k] = (const float*)d_in[bbi[k]] + of[k];
    bp.m[k] = (const float*)d_in[mi[k]]  + of[k];
    bp.v[k] = (const float*)d_in[vi[k]]  + of[k];
  }

  bn_pre_kernel<<<9, 128, 0, stream>>>(bp, bns);
  mega_kernel<<<GRID_FPS + GRID_KM + GRID_POS, 512, 0, stream>>>(
      xyz, feat, te_w, pre_w1, pre_w2, pos_w1, pos_w2, bns,
      fps_idx, x_mid, done, out_xyz, out_x);
}

// Round 3
// 3024.310 us; speedup vs baseline: 1.1450x; 1.0568x over previous
//
#include <hip/hip_runtime.h>

typedef unsigned short u16;
typedef unsigned int   u32;
typedef unsigned long long u64;

#define B_    8
#define N_    8192
#define CIN   64
#define COUT  128
#define NS    2048
#define K_    32
#define LDSPAD 136   // 128 + 8 bf16: breaks bank conflicts on column stride

typedef __attribute__((ext_vector_type(8))) short short8;
typedef __attribute__((ext_vector_type(4))) float f32x4;

#define MFMA16(a,b,c) __builtin_amdgcn_mfma_f32_16x16x32_bf16(a,b,c,0,0,0)

__device__ __forceinline__ u16 f2bf(float f){
  u32 u = __float_as_uint(f);
  return (u16)((u + 0x7FFFu + ((u >> 16) & 1u)) >> 16);   // RNE, finite values only
}
__device__ __forceinline__ float bf2f(u16 h){ u32 u = ((u32)h) << 16; return __uint_as_float(u); }
__device__ __forceinline__ u32 pack2bf(float lo, float hi){ return (u32)f2bf(lo) | ((u32)f2bf(hi) << 16); }

// ---------------------------------------------------------------------------
// Weight f32 -> bf16 conversion (one-time prep into ws)
// ---------------------------------------------------------------------------
__global__ void wcvt_kernel(const float* __restrict__ s, u16* __restrict__ d, int n){
  int i = blockIdx.x * 256 + threadIdx.x;
  if (i < n) d[i] = f2bf(s[i]);
}

// fps_idx -> -1 sentinel, done flags -> 0 (per launch; graph replay reuses ws)
__global__ void clear_kernel(int* __restrict__ fps_idx, u32* __restrict__ done){
  int i = blockIdx.x * 256 + threadIdx.x;
  if (i < B_*NS){ fps_idx[i] = -1; done[i] = 0u; }
}

// ---------------------------------------------------------------------------
// BN constants: scale = g/sqrt(v+eps), bias = b - m*scale  (all f32 inputs)
// set order: 0=te, 1/2=pre0.bn1/bn2, 3/4=pre1.bn1/bn2, 5/6=pos0, 7/8=pos1
// ---------------------------------------------------------------------------
struct BnPtrs { const float* g[9]; const float* b[9]; const float* m[9]; const float* v[9]; };

__global__ void bn_pre_kernel(BnPtrs p, float* __restrict__ bns){
  int set = blockIdx.x, c = threadIdx.x;
  float sc = p.g[set][c] / sqrtf(p.v[set][c] + 1e-5f);
  bns[set*256 + c]       = sc;
  bns[set*256 + 128 + c] = p.b[set][c] - p.m[set][c] * sc;
}

// ---------------------------------------------------------------------------
// MEGA-KERNEL. Round-2 lesson: the per-step RELEASE store stalled the fps
// barrier (vmcnt(0) drain to L3, ~1000cyc under spin-herd contention on the
// same lines). Round-3 fix: (a) publish fps_idx in batches of 8 via RELAXED
// agent stores from wave-0 lanes 0..7 (ack amortized 8x); (b) one poller
// thread per consumer block gates the whole block on slot g0+7 (batches are
// {8k+1..8k+8}: slot 8k+7 published => 8k..8k+6 published earlier or same
// batch), then each wave re-verifies its own slot (intra-batch stores are
// not mutually ordered). Spin traffic drops ~2000x.
//   blocks 0..7        : fps (one batch each; 1 block/CU via 98KB LDS union)
//   blocks 8..2055     : knn+mid fused, 8 centers/block (1 wave/center)
//   blocks 2056..2119  : pos, 8 col-groups/block; spin done[], acquire fence
// ---------------------------------------------------------------------------
struct ShFps {
  __align__(16) f32x4 PX4[4*512];
  __align__(16) f32x4 PY4[4*512];
  __align__(16) f32x4 PZ4[4*512];
  u64  kArr[2][8];
  float xA[2][8], yA[2][8], zA[2][8];
};
struct ShMid {
  __align__(16) u16 X[8][32*LDSPAD];
  __align__(16) float scr[8][128];
};
struct ShPos {
  __align__(16) u16 X[8][32*LDSPAD];
};
union ShAll { ShFps f; ShMid m; ShPos p; };   // 98.6 KB -> 1 block/CU

// ---------------------------------------------------------------------------
// FPS v5 core (2215us standalone): DPP-based reduce, serial-latency bound on
// one CU per batch. Exact f32 (contract off); tie -> lowest index.
// ---------------------------------------------------------------------------
#define DPP_UMAX(x, ctrl) { \
  u32 o = (u32)__builtin_amdgcn_update_dpp((int)(x), (int)(x), ctrl, 0xf, 0xf, false); \
  x = (o > x) ? o : x; }

__device__ __forceinline__ u32 wave_umax63(u32 x){
  DPP_UMAX(x, 0x111)  // row_shr:1
  DPP_UMAX(x, 0x112)  // row_shr:2
  DPP_UMAX(x, 0x114)  // row_shr:4
  DPP_UMAX(x, 0x118)  // row_shr:8
  DPP_UMAX(x, 0x142)  // row_bcast:15
  DPP_UMAX(x, 0x143)  // row_bcast:31
  return (u32)__builtin_amdgcn_readlane((int)x, 63);
}

#define FPS_STEP4(j) { \
  f32x4 xv = PX4[j*512 + t]; \
  f32x4 yv = PY4[j*512 + t]; \
  f32x4 zv = PZ4[j*512 + t]; \
  FPS_ONE(j,0) FPS_ONE(j,1) FPS_ONE(j,2) FPS_ONE(j,3) }

#define FPS_ONE(j,i) { \
  float dx = xv[i] - lx; \
  float dy = yv[i] - ly; \
  float dz = zv[i] - lz; \
  float t0 = dx*dx; \
  float t1 = dy*dy; \
  float t2 = dz*dz; \
  float dd = (t0 + t1) + t2;  /* same assoc as np.sum axis=-1 */ \
  float nd = fminf(D##j##i, dd); \
  D##j##i = nd; \
  u32 nb = __float_as_uint(nd); \
  tb##j = (nb > tb##j) ? nb : tb##j; }

#define FPS_KMIN(j,i) \
  kk = (__float_as_uint(D##j##i) == wmax && (4*j+i) < kk) ? (4*j+i) : kk;

__device__ void fps_path(const float* __restrict__ xyz, int* __restrict__ fps_idx,
                         ShFps& S, int b, int t){
  #pragma clang fp contract(off)
  const int lane = t & 63, wv = t >> 6;
  const float* xb = xyz + (size_t)b * N_ * 3;
  f32x4* PX4 = S.PX4; f32x4* PY4 = S.PY4; f32x4* PZ4 = S.PZ4;
  const int base = t * 16;
  #pragma unroll
  for (int j = 0; j < 4; ++j){                  // one-time transpose stage-in
    f32x4 xv, yv, zv;
    #pragma unroll
    for (int i = 0; i < 4; ++i){
      const int p = base + 4*j + i;
      xv[i] = xb[p*3 + 0];
      yv[i] = xb[p*3 + 1];
      zv[i] = xb[p*3 + 2];
    }
    PX4[j*512 + t] = xv; PY4[j*512 + t] = yv; PZ4[j*512 + t] = zv;
  }
  if (t == 0)
    __hip_atomic_store(fps_idx + b*NS, 0, __ATOMIC_RELAXED, __HIP_MEMORY_SCOPE_AGENT);
  __syncthreads();
  float D00=1e10f,D01=1e10f,D02=1e10f,D03=1e10f;
  float D10=1e10f,D11=1e10f,D12=1e10f,D13=1e10f;
  float D20=1e10f,D21=1e10f,D22=1e10f,D23=1e10f;
  float D30=1e10f,D31=1e10f,D32=1e10f,D33=1e10f;
  const float* PXs = (const float*)PX4;
  const float* PYs = (const float*)PY4;
  const float* PZs = (const float*)PZ4;
  float lx = PXs[0], ly = PYs[0], lz = PZs[0];  // point 0 is the seed
  int my_pi = 0;                                // batched-publish register slot
  for (int s = 0; s < NS - 1; ++s){
    u32 tb0 = 0, tb1 = 0, tb2 = 0, tb3 = 0;     // dist >= 0 -> bits valid for umax
    FPS_STEP4(0) FPS_STEP4(1) FPS_STEP4(2) FPS_STEP4(3)
    u32 ta = (tb0 > tb1) ? tb0 : tb1;
    u32 tc = (tb2 > tb3) ? tb2 : tb3;
    u32 tbm = (ta > tc) ? ta : tc;              // per-thread max (4+2 tree)
    const u32 wmax = wave_umax63(tbm);          // 6 VALU DPP ops + readlane
    const u64 mask = __ballot(tbm == wmax);
    const int fl = __ffsll((long long)mask) - 1;   // lowest lane = lowest index
    const int sl = s & 1;
    if (lane == fl){
      int kk = 64;
      FPS_KMIN(0,0) FPS_KMIN(0,1) FPS_KMIN(0,2) FPS_KMIN(0,3)
      FPS_KMIN(1,0) FPS_KMIN(1,1) FPS_KMIN(1,2) FPS_KMIN(1,3)
      FPS_KMIN(2,0) FPS_KMIN(2,1) FPS_KMIN(2,2) FPS_KMIN(2,3)
      FPS_KMIN(3,0) FPS_KMIN(3,1) FPS_KMIN(3,2) FPS_KMIN(3,3)
      const int pi = base + kk;                  // first max index in this wave
      S.kArr[sl][wv] = ((u64)wmax << 13) | (u64)(8191 - pi);
      const int li = ((kk >> 2)*512 + t)*4 + (kk & 3);
      S.xA[sl][wv] = PXs[li]; S.yA[sl][wv] = PYs[li]; S.zA[sl][wv] = PZs[li];
    }
    __syncthreads();
    // parallel load of all 8 records, then cndmask select (no dependent load)
    u64 win = S.kArr[sl][0];
    float cx = S.xA[sl][0], cy = S.yA[sl][0], cz = S.zA[sl][0];
    #pragma unroll
    for (int w = 1; w < 8; ++w){
      u64 o = S.kArr[sl][w];
      float ox = S.xA[sl][w], oy = S.yA[sl][w], oz = S.zA[sl][w];
      bool c = o > win;
      win = c ? o : win; cx = c ? ox : cx; cy = c ? oy : cy; cz = c ? oz : cz;
    }
    lx = cx; ly = cy; lz = cz;
    // batched publish: step s fills lane (s&7)'s register; at s&7==7 wave-0
    // lanes 0..7 store slots s-6..s+1 (relaxed agent: write-through, no drain)
    const int pi_out = 8191 - (int)(win & 0x1FFFull);
    if (lane == (s & 7)) my_pi = pi_out;
    if ((s & 7) == 7 && t < 8)
      __hip_atomic_store(fps_idx + b*NS + s - 6 + t, my_pi,
                         __ATOMIC_RELAXED, __HIP_MEMORY_SCOPE_AGENT);
  }
  // steps 2040..2046 filled lanes 0..6 -> slots 2041..2047
  if (t < 7)
    __hip_atomic_store(fps_idx + b*NS + (NS - 7) + t, my_pi,
                       __ATOMIC_RELAXED, __HIP_MEMORY_SCOPE_AGENT);
}

// ---------------------------------------------------------------------------
// Conv stack helpers (unchanged, m89-verified MFMA layouts).
// ---------------------------------------------------------------------------
__device__ __forceinline__ void zero_acc(f32x4 acc[8][2]){
  #pragma unroll
  for (int mt = 0; mt < 8; ++mt)
    #pragma unroll
    for (int nt = 0; nt < 2; ++nt){
      acc[mt][nt][0] = 0.f; acc[mt][nt][1] = 0.f; acc[mt][nt][2] = 0.f; acc[mt][nt][3] = 0.f;
    }
}

__device__ __forceinline__ void conv_step(const u16* __restrict__ W, const u16* __restrict__ Xw,
                                          int q, int l15, f32x4 acc[8][2]){
  #pragma unroll
  for (int kk = 0; kk < 4; ++kk){
    short8 b0 = *(const short8*)(Xw + l15*LDSPAD + kk*32 + q*8);
    short8 b1 = *(const short8*)(Xw + (16 + l15)*LDSPAD + kk*32 + q*8);
    #pragma unroll
    for (int mt = 0; mt < 8; ++mt){
      short8 a = *(const short8*)(W + (size_t)(mt*16 + l15)*COUT + kk*32 + q*8);
      acc[mt][0] = MFMA16(a, b0, acc[mt][0]);
      acc[mt][1] = MFMA16(a, b1, acc[mt][1]);
    }
  }
}

// y1 = relu(bn1(W1@X)); out = relu(bn2(W2@y1) + resid). Leaves post-relu f32 in acc.
__device__ __forceinline__ void res_block(const u16* __restrict__ W1, const u16* __restrict__ W2,
    const float* __restrict__ bn1, const float* __restrict__ bn2,
    u16* __restrict__ Xw, int q, int l15, u32 resid[8][2][2], f32x4 acc[8][2], bool writeback){
  zero_acc(acc);
  conv_step(W1, Xw, q, l15, acc);
  #pragma unroll
  for (int mt = 0; mt < 8; ++mt){
    f32x4 sc = *(const f32x4*)(bn1 + mt*16 + q*4);
    f32x4 bi = *(const f32x4*)(bn1 + 128 + mt*16 + q*4);
    #pragma unroll
    for (int nt = 0; nt < 2; ++nt){
      float y0 = fmaxf(fmaf(acc[mt][nt][0], sc[0], bi[0]), 0.f);
      float y1 = fmaxf(fmaf(acc[mt][nt][1], sc[1], bi[1]), 0.f);
      float y2 = fmaxf(fmaf(acc[mt][nt][2], sc[2], bi[2]), 0.f);
      float y3 = fmaxf(fmaf(acc[mt][nt][3], sc[3], bi[3]), 0.f);
      *(uint2*)(Xw + (nt*16 + l15)*LDSPAD + mt*16 + q*4) = make_uint2(pack2bf(y0,y1), pack2bf(y2,y3));
    }
  }
  __syncthreads();
  zero_acc(acc);
  conv_step(W2, Xw, q, l15, acc);
  #pragma unroll
  for (int mt = 0; mt < 8; ++mt){
    f32x4 sc = *(const f32x4*)(bn2 + mt*16 + q*4);
    f32x4 bi = *(const f32x4*)(bn2 + 128 + mt*16 + q*4);
    #pragma unroll
    for (int nt = 0; nt < 2; ++nt){
      float r0 = bf2f((u16)(resid[mt][nt][0] & 0xFFFFu));
      float r1 = bf2f((u16)(resid[mt][nt][0] >> 16));
      float r2 = bf2f((u16)(resid[mt][nt][1] & 0xFFFFu));
      float r3 = bf2f((u16)(resid[mt][nt][1] >> 16));
      float y0 = fmaxf(fmaf(acc[mt][nt][0], sc[0], bi[0]) + r0, 0.f);
      float y1 = fmaxf(fmaf(acc[mt][nt][1], sc[1], bi[1]) + r1, 0.f);
      float y2 = fmaxf(fmaf(acc[mt][nt][2], sc[2], bi[2]) + r2, 0.f);
      float y3 = fmaxf(fmaf(acc[mt][nt][3], sc[3], bi[3]) + r3, 0.f);
      acc[mt][nt][0] = y0; acc[mt][nt][1] = y1; acc[mt][nt][2] = y2; acc[mt][nt][3] = y3;
      if (writeback){
        u32 p0 = pack2bf(y0,y1), p1 = pack2bf(y2,y3);
        resid[mt][nt][0] = p0; resid[mt][nt][1] = p1;
        *(uint2*)(Xw + (nt*16 + l15)*LDSPAD + mt*16 + q*4) = make_uint2(p0, p1);
      }
    }
  }
  if (writeback) __syncthreads();
}

// ---------------------------------------------------------------------------
// knn (register-resident result) + mid, one wave per center. Block-level gate
// already passed; per-wave verify spin (intra-batch stores unordered).
// ---------------------------------------------------------------------------
__device__ void knnmid_path(const float* __restrict__ xyz, const float* __restrict__ feat,
    const u16* __restrict__ te_w, const u16* __restrict__ pre_w1, const u16* __restrict__ pre_w2,
    const float* __restrict__ bns, int* __restrict__ fps_idx,
    u16* __restrict__ x_mid, u32* __restrict__ done, float* __restrict__ out_xyz,
    u16* __restrict__ Xw, float* __restrict__ scrw, int g, int lane){
  #pragma clang fp contract(off)
  const int b = g >> 11;
  const float* xb = xyz + (size_t)b * N_ * 3;

  int raw;
  for (;;){
    raw = __hip_atomic_load(fps_idx + g, __ATOMIC_RELAXED, __HIP_MEMORY_SCOPE_AGENT);
    if (raw >= 0) break;     // usually already visible (block gate passed)
    __builtin_amdgcn_s_sleep(2);
  }
  const int ci = raw & (N_ - 1);                // clamp: fault-proof
  const float cx = xb[ci*3], cy = xb[ci*3+1], cz = xb[ci*3+2];
  if (lane < 3) out_xyz[g*3 + lane] = xb[ci*3 + lane];

  // --- knn: sorted 64-slot lane list, threshold slot 31 (exact f32 + lex tie)
  float rd = __uint_as_float(0x7F800000u); int ri = 0x7FFFFFFF;
  float r31d = rd; int r31i = ri;
  for (int c = 0; c < N_/64; ++c){
    const int pid = c*64 + lane;
    float dx = xb[pid*3]   - cx;
    float dy = xb[pid*3+1] - cy;
    float dz = xb[pid*3+2] - cz;
    float t0 = dx*dx, t1 = dy*dy, t2 = dz*dz;
    float d2 = (t0 + t1) + t2;
    u64 m = __ballot((d2 < r31d) || (d2 == r31d && pid < r31i));
    while (m){
      int l = __ffsll((long long)m) - 1; m &= m - 1;
      float v = __shfl(d2, l); int vi = c*64 + l;
      if (!((v < r31d) || (v == r31d && vi < r31i))) continue;  // re-check vs updated threshold
      bool lt = (rd < v) || (rd == v && ri < vi);
      int pos = __popcll(__ballot(lt));
      float prd = __shfl_up(rd, 1); int pri = __shfl_up(ri, 1);
      if (lane == pos){ rd = v; ri = vi; }
      else if (lane > pos){ rd = prd; ri = pri; }
      r31d = __shfl(rd, 31); r31i = __shfl(ri, 31);
    }
  }
  // neighbor k (k<32) lives in lane k's ri - handed to mid via shfl below.

  // --- mid: gather -> te conv -> 2 pre res-blocks -> maxpool
  const int q = lane >> 4, l15 = lane & 15;
  const float* fb = feat + (size_t)b * N_ * CIN;
  #pragma unroll
  for (int it = 0; it < 4; ++it){
    int lidx = it*64 + lane;
    int kq = lidx & 7;                            // 8-ch chunk
    int col = it*8 + (lane >> 3);                 // col<32
    int nb = __shfl(ri, col) & (N_ - 1);
    f32x4 a0 = *(const f32x4*)(fb + (size_t)nb*CIN + kq*8);
    f32x4 a1 = *(const f32x4*)(fb + (size_t)nb*CIN + kq*8 + 4);
    *(uint2*)(Xw + col*LDSPAD + kq*8)     = make_uint2(pack2bf(a0[0],a0[1]), pack2bf(a0[2],a0[3]));
    *(uint2*)(Xw + col*LDSPAD + kq*8 + 4) = make_uint2(pack2bf(a1[0],a1[1]), pack2bf(a1[2],a1[3]));
    f32x4 c0 = *(const f32x4*)(fb + (size_t)ci*CIN + kq*8);
    f32x4 c1 = *(const f32x4*)(fb + (size_t)ci*CIN + kq*8 + 4);
    *(uint2*)(Xw + col*LDSPAD + 64 + kq*8)     = make_uint2(pack2bf(c0[0],c0[1]), pack2bf(c0[2],c0[3]));
    *(uint2*)(Xw + col*LDSPAD + 64 + kq*8 + 4) = make_uint2(pack2bf(c1[0],c1[1]), pack2bf(c1[2],c1[3]));
  }
  __syncthreads();

  f32x4 acc[8][2];
  u32 resid[8][2][2];
  zero_acc(acc);
  conv_step(te_w, Xw, q, l15, acc);
  #pragma unroll
  for (int mt = 0; mt < 8; ++mt){
    f32x4 sc = *(const f32x4*)(bns + mt*16 + q*4);
    f32x4 bi = *(const f32x4*)(bns + 128 + mt*16 + q*4);
    #pragma unroll
    for (int nt = 0; nt < 2; ++nt){
      float y0 = fmaxf(fmaf(acc[mt][nt][0], sc[0], bi[0]), 0.f);
      float y1 = fmaxf(fmaf(acc[mt][nt][1], sc[1], bi[1]), 0.f);
      float y2 = fmaxf(fmaf(acc[mt][nt][2], sc[2], bi[2]), 0.f);
      float y3 = fmaxf(fmaf(acc[mt][nt][3], sc[3], bi[3]), 0.f);
      u32 p0 = pack2bf(y0,y1), p1 = pack2bf(y2,y3);
      resid[mt][nt][0] = p0; resid[mt][nt][1] = p1;
      *(uint2*)(Xw + (nt*16 + l15)*LDSPAD + mt*16 + q*4) = make_uint2(p0, p1);
    }
  }
  __syncthreads();

  res_block(pre_w1,             pre_w2,             bns + 256, bns + 512,  Xw, q, l15, resid, acc, true);
  res_block(pre_w1 + COUT*COUT, pre_w2 + COUT*COUT, bns + 768, bns + 1024, Xw, q, l15, resid, acc, false);

  // maxpool over 32 cols (nt pair + butterfly over low-4 lane bits)
  float mx[8][4];
  #pragma unroll
  for (int mt = 0; mt < 8; ++mt)
    #pragma unroll
    for (int r = 0; r < 4; ++r){
      float m0 = fmaxf(acc[mt][0][r], acc[mt][1][r]);
      #pragma unroll
      for (int off = 1; off < 16; off <<= 1) m0 = fmaxf(m0, __shfl_xor(m0, off));
      mx[mt][r] = m0;
    }
  if (l15 == 0){
    #pragma unroll
    for (int mt = 0; mt < 8; ++mt){
      f32x4 vv; vv[0] = mx[mt][0]; vv[1] = mx[mt][1]; vv[2] = mx[mt][2]; vv[3] = mx[mt][3];
      *(f32x4*)(scrw + mt*16 + q*4) = vv;
    }
  }
  __syncthreads();
  float v0 = scrw[lane*2], v1 = scrw[lane*2 + 1];
  *(u32*)(x_mid + (size_t)g*COUT + lane*2) = pack2bf(v0, v1);
  if (lane == 0)   // release: s_waitcnt is wave-level -> covers all lanes' stores
    __hip_atomic_store(done + g, 1u, __ATOMIC_RELEASE, __HIP_MEMORY_SCOPE_AGENT);
}

// ---------------------------------------------------------------------------
// pos: 2 res-blocks over (B,128,2048); one wave per 32 columns. Spins on the
// 32 done flags of its column group, acquire-fences, then reads x_mid.
// ---------------------------------------------------------------------------
__device__ void pos_path(const u16* __restrict__ x_mid,
    const u16* __restrict__ pos_w1, const u16* __restrict__ pos_w2,
    const float* __restrict__ bns, float* __restrict__ out_x,
    u32* __restrict__ done, u16* __restrict__ Xw, int g, int lane){
  const int q = lane >> 4, l15 = lane & 15;
  const int gc0 = g * 32;
  const int b = gc0 >> 11, s0 = gc0 & 2047;
  for (;;){
    u32 d = (lane < 32)
      ? __hip_atomic_load(done + gc0 + lane, __ATOMIC_RELAXED, __HIP_MEMORY_SCOPE_AGENT)
      : 1u;
    if (__all(d != 0)) break;
    __builtin_amdgcn_s_sleep(16);
  }
  __builtin_amdgcn_fence(__ATOMIC_ACQUIRE, "agent");
  #pragma unroll
  for (int it = 0; it < 8; ++it){
    int lidx = it*64 + lane;
    int col = lidx >> 4, kq = lidx & 15;
    uint4 v = *(const uint4*)(x_mid + (size_t)(gc0 + col)*COUT + kq*8);
    *(uint4*)(Xw + col*LDSPAD + kq*8) = v;
  }
  __syncthreads();
  u32 resid[8][2][2];
  #pragma unroll
  for (int mt = 0; mt < 8; ++mt)
    #pragma unroll
    for (int nt = 0; nt < 2; ++nt){
      uint2 rr = *(const uint2*)(Xw + (nt*16 + l15)*LDSPAD + mt*16 + q*4);
      resid[mt][nt][0] = rr.x; resid[mt][nt][1] = rr.y;
    }
  f32x4 acc[8][2];
  res_block(pos_w1,             pos_w2,             bns + 1280, bns + 1536, Xw, q, l15, resid, acc, true);
  res_block(pos_w1 + COUT*COUT, pos_w2 + COUT*COUT, bns + 1792, bns + 2048, Xw, q, l15, resid, acc, false);
  #pragma unroll
  for (int mt = 0; mt < 8; ++mt)
    #pragma unroll
    for (int nt = 0; nt < 2; ++nt)
      #pragma unroll
      for (int r = 0; r < 4; ++r){
        int row = mt*16 + q*4 + r;
        int colx = s0 + nt*16 + l15;
        out_x[(size_t)(b*COUT + row)*NS + colx] = acc[mt][nt][r];
      }
}

// ---------------------------------------------------------------------------
#define GRID_FPS    B_                 // 8
#define GRID_KM     (B_*NS/8)          // 2048 blocks x 8 waves = 16384 centers
#define GRID_POS    (B_*NS/K_/8)       // 64 blocks x 8 waves = 512 groups

__global__ __launch_bounds__(512) void mega_kernel(
    const float* __restrict__ xyz, const float* __restrict__ feat,
    const u16* __restrict__ te_w, const u16* __restrict__ pre_w1, const u16* __restrict__ pre_w2,
    const u16* __restrict__ pos_w1, const u16* __restrict__ pos_w2,
    const float* __restrict__ bns, int* __restrict__ fps_idx,
    u16* __restrict__ x_mid, u32* __restrict__ done,
    float* __restrict__ out_xyz, float* __restrict__ out_x){
  __shared__ ShAll sh;
  const int bid = blockIdx.x;
  const int t = threadIdx.x;
  const int wid = t >> 6, lane = t & 63;
  if (bid < GRID_FPS){
    fps_path(xyz, fps_idx, sh.f, bid, t);
  } else if (bid < GRID_FPS + GRID_KM){
    const int g0 = (bid - GRID_FPS)*8;
    // block gate: slot g0+7 published => slots g0..g0+6 published earlier or
    // in the same batch (batches are {8k+1..8k+8}; slot 0 stored at init).
    // ONE scalar poller per block -> ~2000x less L3 spin traffic.
    if (t == 0){
      while (__hip_atomic_load(fps_idx + g0 + 7, __ATOMIC_RELAXED,
                               __HIP_MEMORY_SCOPE_AGENT) < 0)
        __builtin_amdgcn_s_sleep(16);
    }
    __syncthreads();
    knnmid_path(xyz, feat, te_w, pre_w1, pre_w2, bns, fps_idx, x_mid, done, out_xyz,
                sh.m.X[wid], sh.m.scr[wid], g0 + wid, lane);
  } else {
    const int g = (bid - GRID_FPS - GRID_KM)*8 + wid;
    pos_path(x_mid, pos_w1, pos_w2, bns, out_x, done, sh.p.X[wid], g, lane);
  }
}

// ---------------------------------------------------------------------------
extern "C" void kernel_launch(void* const* d_in, const int* in_sizes, int n_in,
                              void* d_out, int out_size, void* d_ws, size_t ws_size,
                              hipStream_t stream){
  (void)in_sizes; (void)n_in; (void)out_size; (void)ws_size;
  const float* xyz    = (const float*)d_in[0];
  const float* feat   = (const float*)d_in[1];

  // ws layout (16B aligned, ~4.7 MB total):
  char* ws = (char*)d_ws;
  float* bns     = (float*)ws;                          // 16 KiB (9.2 used)
  u16*   wbf     = (u16*)(ws + 16384);                  // 288 KiB bf16 weights
  int*   fps_idx = (int*)(ws + 16384 + 294912);         // 64 KiB
  u32*   done    = (u32*)(ws + 16384 + 294912 + 65536); // 64 KiB
  u16*   x_mid   = (u16*)(ws + 16384 + 294912 + 65536 + 65536); // 4 MiB
  float* out_xyz = (float*)d_out;                       // (8,2048,3) f32
  float* out_x   = (float*)d_out + B_*NS*3;             // (8,128,2048) f32

  // bf16 weight staging: te(16384) pre_w1(32768) pre_w2(32768) pos_w1(32768) pos_w2(32768)
  u16* te_w   = wbf;
  u16* pre_w1 = wbf + 16384;
  u16* pre_w2 = wbf + 49152;
  u16* pos_w1 = wbf + 81920;
  u16* pos_w2 = wbf + 114688;
  wcvt_kernel<<<64,  256, 0, stream>>>((const float*)d_in[2],  te_w,   16384);
  wcvt_kernel<<<128, 256, 0, stream>>>((const float*)d_in[7],  pre_w1, 32768);
  wcvt_kernel<<<128, 256, 0, stream>>>((const float*)d_in[8],  pre_w2, 32768);
  wcvt_kernel<<<128, 256, 0, stream>>>((const float*)d_in[17], pos_w1, 32768);
  wcvt_kernel<<<128, 256, 0, stream>>>((const float*)d_in[18], pos_w2, 32768);
  clear_kernel<<<64, 256, 0, stream>>>(fps_idx, done);

  // dict order: te_g/b/m/v = 3..6 ; pre: w1,w2,g1,g2,b1,b2,m1,m2,v1,v2 = 7..16 ; pos = 17..26
  BnPtrs bp;
  const int gi[9] = {3, 9, 10, 9, 10, 19, 20, 19, 20};
  const int bbi[9]= {4, 11,12, 11,12, 21, 22, 21, 22};
  const int mi[9] = {5, 13,14, 13,14, 23, 24, 23, 24};
  const int vi[9] = {6, 15,16, 15,16, 25, 26, 25, 26};
  const int of[9] = {0, 0, 0, 128,128, 0, 0, 128,128};
  for (int k = 0; k < 9; ++k){
    bp.g[k] = (const float*)d_in[gi[k]]  + of[k];
    bp.b[k] = (const float*)d_in[bbi[k]] + of[k];
    bp.m[k] = (const float*)d_in[mi[k]]  + of[k];
    bp.v[k] = (const float*)d_in[vi[k]]  + of[k];
  }

  bn_pre_kernel<<<9, 128, 0, stream>>>(bp, bns);
  mega_kernel<<<GRID_FPS + GRID_KM + GRID_POS, 512, 0, stream>>>(
      xyz, feat, te_w, pre_w1, pre_w2, pos_w1, pos_w2, bns,
      fps_idx, x_mid, done, out_xyz, out_x);
}